// Round 2
// baseline (1883.322 us; speedup 1.0000x reference)
//
#include <hip/hip_runtime.h>

// Problem constants (fixed by reference)
constexpr int Bn = 4;
constexpr int Nn = 1024;
constexpr int Cn = 768;
constexpr int Hn = 12;
constexpr int Dn = 64;
constexpr float SCALE_Q = 0.125f;          // D^-0.5
constexpr int SEG = Bn * Nn * Cn;          // 3,145,728 (= B*H*N*D as well)
constexpr int HND = Hn * Nn * Dn;          // 786,432
constexpr int NDn = Nn * Dn;               // 65,536

// XOR swizzle for [64][64] fp32 LDS tiles accessed as float4 slots (16 per row):
// slot' = slot ^ (row & 7) -> conflict-free b128 reads down columns.
__device__ __forceinline__ int swz4(int row, int s) {
    return (row << 6) + ((s ^ (row & 7)) << 2);
}
__device__ __forceinline__ int swz1(int row, int d) {
    return (row << 6) + ((((d >> 2) ^ (row & 7)) << 2) | (d & 3));
}
__device__ __forceinline__ float dot4(float4 a, float4 b, float acc) {
    acc = fmaf(a.x, b.x, acc);
    acc = fmaf(a.y, b.y, acc);
    acc = fmaf(a.z, b.z, acc);
    return fmaf(a.w, b.w, acc);
}

// ---------------------------------------------------------------------------
// Y = A @ W^T   A:[4096,768] row-major, W:[Nout,768] row-major (torch Linear).
// MODE 0 (qkv): grid.z selects primal/jvp input; scatter to q/k/v arrays in
//               [B][H][N][D] layout; scale the q third by SCALE_Q.
// MODE 1 (proj): write O[row*768+col] (+bias for z==0 only).
// ---------------------------------------------------------------------------
template<int MODE>
__global__ __launch_bounds__(256)
void gemm_k(const float* __restrict__ A0, const float* __restrict__ A1,
            const float* __restrict__ W, const float* __restrict__ bias,
            float* __restrict__ O0, float* __restrict__ O1)
{
    __shared__ float As[16][68];   // [k][m], pad 68 keeps 16B alignment, no conflicts
    __shared__ float Bs[16][68];   // [k][n]
    const int tid = threadIdx.x;
    const int z = blockIdx.z;
    const float* __restrict__ A = z ? A1 : A0;
    const int row0 = blockIdx.y << 6;
    const int col0 = blockIdx.x << 6;
    const int lr = tid >> 2;          // 0..63 load row
    const int lk = (tid & 3) << 2;    // 0,4,8,12
    const int tm = tid >> 4;          // 0..15
    const int tn = tid & 15;          // 0..15

    const float* __restrict__ Ap = A + (size_t)(row0 + lr) * Cn + lk;
    const float* __restrict__ Wp = W + (size_t)(col0 + lr) * Cn + lk;

    float acc[4][4] = {};

    for (int k0 = 0; k0 < Cn; k0 += 16) {
        const float4 a4 = *(const float4*)(Ap + k0);
        const float4 b4 = *(const float4*)(Wp + k0);
        __syncthreads();
        As[lk + 0][lr] = a4.x; As[lk + 1][lr] = a4.y;
        As[lk + 2][lr] = a4.z; As[lk + 3][lr] = a4.w;
        Bs[lk + 0][lr] = b4.x; Bs[lk + 1][lr] = b4.y;
        Bs[lk + 2][lr] = b4.z; Bs[lk + 3][lr] = b4.w;
        __syncthreads();
#pragma unroll
        for (int kk = 0; kk < 16; ++kk) {
            const float4 av = *(const float4*)&As[kk][tm << 2];
            const float4 bv = *(const float4*)&Bs[kk][tn << 2];
            const float aa[4] = {av.x, av.y, av.z, av.w};
            const float bb[4] = {bv.x, bv.y, bv.z, bv.w};
#pragma unroll
            for (int i = 0; i < 4; ++i)
#pragma unroll
                for (int j = 0; j < 4; ++j)
                    acc[i][j] = fmaf(aa[i], bb[j], acc[i][j]);
        }
    }

    if (MODE == 0) {
        // col tile (64 wide) maps to exactly one (t,h): 64 | 768, 64 == D
        const int t = col0 / Cn;              // 0=q 1=k 2=v
        const int h = (col0 % Cn) >> 6;       // head
        const float s = (t == 0) ? SCALE_Q : 1.0f;
        float* __restrict__ dst =
            (z ? O1 : O0) + (size_t)t * SEG + (size_t)h * NDn + (tn << 2);
#pragma unroll
        for (int i = 0; i < 4; ++i) {
            const int row = row0 + (tm << 2) + i;   // b*N + n
            const int b = row >> 10;
            const int n = row & 1023;
            float4 o;
            o.x = acc[i][0] * s; o.y = acc[i][1] * s;
            o.z = acc[i][2] * s; o.w = acc[i][3] * s;
            *(float4*)(dst + (size_t)b * HND + ((size_t)n << 6)) = o;
        }
    } else {
        float* __restrict__ O = z ? O1 : O0;
        const int colb = col0 + (tn << 2);
        float4 bi = make_float4(0.f, 0.f, 0.f, 0.f);
        if (z == 0) bi = *(const float4*)(bias + colb);
#pragma unroll
        for (int i = 0; i < 4; ++i) {
            const int row = row0 + (tm << 2) + i;
            float4 o;
            o.x = acc[i][0] + bi.x; o.y = acc[i][1] + bi.y;
            o.z = acc[i][2] + bi.z; o.w = acc[i][3] + bi.w;
            *(float4*)(O + (size_t)row * Cn + colb) = o;
        }
    }
}

// Stage a 64x64 fp32 tile (row stride 64 in global) into swizzled LDS.
__device__ __forceinline__ void stage64(float* __restrict__ dst,
                                        const float* __restrict__ src, int tid)
{
    const int rr = tid >> 4;     // 0..31
    const int s = tid & 15;      // float4 slot
#pragma unroll
    for (int p = 0; p < 2; ++p) {
        const int row = rr + (p << 5);
        const float4 t4 = *(const float4*)(src + (row << 6) + (s << 2));
        *(float4*)(dst + swz4(row, s)) = t4;
    }
}

// ---------------------------------------------------------------------------
// Fused attention + softmax-JVP. One block = (b*h, 16 query rows), 512 threads.
// Full score row kept in LDS -> exact softmax, then streaming recompute of
// dm = qj.k^T + q.kj^T with fused accumulation of x, C_jvp, sum(e*dm*v), sum(e*dm).
// ---------------------------------------------------------------------------
__global__ __launch_bounds__(512)
void attn_k(const float* __restrict__ wsq, float* __restrict__ xatt,
            float* __restrict__ xattj)
{
    __shared__ float sS[16 * 1024];   // 64 KB: scores -> e values
    __shared__ float sQ[16 * 64];
    __shared__ float sQj[16 * 64];
    __shared__ float t0[64 * 64];     // swizzled staging tiles (16 KB each)
    __shared__ float t1[64 * 64];
    __shared__ float t2[64 * 64];
    __shared__ float t3[64 * 64];
    __shared__ float sDM[16 * 68];
    __shared__ float sL[16];

    const int tid = threadIdx.x;
    const int bh = blockIdx.x;        // 0..47
    const int r0 = blockIdx.y << 4;   // query row block

    const float* __restrict__ q  = wsq + (size_t)bh * NDn;
    const float* __restrict__ k  = wsq + 1 * (size_t)SEG + (size_t)bh * NDn;
    const float* __restrict__ v  = wsq + 2 * (size_t)SEG + (size_t)bh * NDn;
    const float* __restrict__ qj = wsq + 3 * (size_t)SEG + (size_t)bh * NDn;
    const float* __restrict__ kj = wsq + 4 * (size_t)SEG + (size_t)bh * NDn;
    const float* __restrict__ vj = wsq + 5 * (size_t)SEG + (size_t)bh * NDn;

    // Phase A: load Q / Qj rows (already scaled by SCALE_Q at qkv epilogue)
    {
        const int which = tid >> 8;           // 0 -> q, 1 -> qj
        const int rr = (tid >> 4) & 15;
        const int dc = (tid & 15) << 2;
        const float* __restrict__ src = which ? qj : q;
        const float4 t4 = *(const float4*)(src + ((r0 + rr) << 6) + dc);
        float* __restrict__ dq = which ? sQj : sQ;
        *(float4*)(dq + (rr << 6) + dc) = t4;
    }
    __syncthreads();

    // Phase B: S[16][1024] = Q @ K^T  (4 K-tiles per iteration)
    {
        const int rowg = tid >> 6;            // 0..7 -> rows 2g,2g+1
        const int cg = tid & 63;
        const int qo0 = rowg << 7;
        const int qo1 = qo0 + 64;
        for (int jt = 0; jt < Nn; jt += 256) {
            stage64(t0, k + ((size_t)(jt + 0) << 6), tid);
            stage64(t1, k + ((size_t)(jt + 64) << 6), tid);
            stage64(t2, k + ((size_t)(jt + 128) << 6), tid);
            stage64(t3, k + ((size_t)(jt + 192) << 6), tid);
            __syncthreads();
            float a0[4] = {};
            float a1[4] = {};
#pragma unroll
            for (int d4 = 0; d4 < 16; ++d4) {
                const float4 q0 = *(const float4*)(sQ + qo0 + (d4 << 2));
                const float4 q1 = *(const float4*)(sQ + qo1 + (d4 << 2));
                const int off = swz4(cg, d4);
                const float4 k0 = *(const float4*)(t0 + off);
                const float4 k1 = *(const float4*)(t1 + off);
                const float4 k2 = *(const float4*)(t2 + off);
                const float4 k3 = *(const float4*)(t3 + off);
                a0[0] = dot4(q0, k0, a0[0]); a0[1] = dot4(q0, k1, a0[1]);
                a0[2] = dot4(q0, k2, a0[2]); a0[3] = dot4(q0, k3, a0[3]);
                a1[0] = dot4(q1, k0, a1[0]); a1[1] = dot4(q1, k1, a1[1]);
                a1[2] = dot4(q1, k2, a1[2]); a1[3] = dot4(q1, k3, a1[3]);
            }
            const int sr0 = (rowg << 1) << 10;
            const int sr1 = sr0 + 1024;
#pragma unroll
            for (int m = 0; m < 4; ++m) {
                sS[sr0 + jt + (m << 6) + cg] = a0[m];
                sS[sr1 + jt + (m << 6) + cg] = a1[m];
            }
            __syncthreads();
        }
    }

    // Phase C: softmax over each row (store unnormalized e, keep l per row)
    {
        const int row = tid >> 5;             // 0..15
        const int l32 = tid & 31;
        float* __restrict__ sr = sS + (row << 10);
        float m = -3.0e38f;
#pragma unroll
        for (int i = 0; i < 32; ++i) m = fmaxf(m, sr[l32 + (i << 5)]);
#pragma unroll
        for (int off = 1; off < 32; off <<= 1) m = fmaxf(m, __shfl_xor(m, off));
        float l = 0.f;
#pragma unroll
        for (int i = 0; i < 32; ++i) {
            const float e = __expf(sr[l32 + (i << 5)] - m);
            sr[l32 + (i << 5)] = e;
            l += e;
        }
#pragma unroll
        for (int off = 1; off < 32; off <<= 1) l += __shfl_xor(l, off);
        if (l32 == 0) sL[row] = l;
    }
    __syncthreads();

    // Phase D: stream k/kj/v/vj, build dm tile, accumulate outputs
    const int rg = tid >> 5;                  // 0..15 (row for accumulate)
    const int dg = tid & 31;                  // d, d+32 columns
    const int rowg = tid >> 6;                // dm-compute mapping
    const int cg = tid & 63;
    float ax0 = 0, ax1 = 0, ac0 = 0, ac1 = 0, ad0 = 0, ad1 = 0, ar = 0;

    for (int jt = 0; jt < Nn; jt += 64) {
        stage64(t0, k + ((size_t)jt << 6), tid);
        stage64(t1, kj + ((size_t)jt << 6), tid);
        stage64(t2, v + ((size_t)jt << 6), tid);
        stage64(t3, vj + ((size_t)jt << 6), tid);
        __syncthreads();
        {
            const int qo0 = rowg << 7;
            const int qo1 = qo0 + 64;
            float dm0 = 0, dm1 = 0;
#pragma unroll
            for (int d4 = 0; d4 < 16; ++d4) {
                const int off = swz4(cg, d4);
                const float4 kk = *(const float4*)(t0 + off);
                const float4 kkj = *(const float4*)(t1 + off);
                const float4 q0 = *(const float4*)(sQ + qo0 + (d4 << 2));
                const float4 q1 = *(const float4*)(sQ + qo1 + (d4 << 2));
                const float4 qj0 = *(const float4*)(sQj + qo0 + (d4 << 2));
                const float4 qj1 = *(const float4*)(sQj + qo1 + (d4 << 2));
                dm0 = dot4(qj0, kk, dm0); dm0 = dot4(q0, kkj, dm0);
                dm1 = dot4(qj1, kk, dm1); dm1 = dot4(q1, kkj, dm1);
            }
            sDM[(rowg << 1) * 68 + cg] = dm0;
            sDM[((rowg << 1) + 1) * 68 + cg] = dm1;
        }
        __syncthreads();
        const float* __restrict__ se = sS + (rg << 10) + jt;
        const float* __restrict__ sd = sDM + rg * 68;
#pragma unroll 16
        for (int j = 0; j < 64; ++j) {
            const float e = se[j];
            const float dm = sd[j];
            const float v0 = t2[swz1(j, dg)];
            const float v1 = t2[swz1(j, dg + 32)];
            const float w0 = t3[swz1(j, dg)];
            const float w1 = t3[swz1(j, dg + 32)];
            const float ed = e * dm;
            ax0 = fmaf(e, v0, ax0);  ax1 = fmaf(e, v1, ax1);
            ac0 = fmaf(e, w0, ac0);  ac1 = fmaf(e, w1, ac1);
            ad0 = fmaf(ed, v0, ad0); ad1 = fmaf(ed, v1, ad1);
            ar += ed;
        }
        __syncthreads();
    }

    // Epilogue: x = ax/l ; row = ar/l ; xj = (ad+ac)/l - row*x
    {
        const int b = bh / Hn;
        const int h = bh - b * Hn;
        const int n = r0 + rg;
        const float invl = 1.0f / sL[rg];
        const float rowv = ar * invl;
        const float x0 = ax0 * invl, x1 = ax1 * invl;
        const float xj0 = fmaf(-rowv, x0, (ad0 + ac0) * invl);
        const float xj1 = fmaf(-rowv, x1, (ad1 + ac1) * invl);
        const size_t base = ((size_t)(b * Nn + n)) * Cn + h * Dn + dg;
        xatt[base] = x0;       xatt[base + 32] = x1;
        xattj[base] = xj0;     xattj[base + 32] = xj1;
    }
}

extern "C" void kernel_launch(void* const* d_in, const int* in_sizes, int n_in,
                              void* d_out, int out_size, void* d_ws, size_t ws_size,
                              hipStream_t stream)
{
    const float* input  = (const float*)d_in[0];
    const float* inputj = (const float*)d_in[1];
    const float* W_qkv  = (const float*)d_in[2];
    const float* W_proj = (const float*)d_in[3];
    const float* b_proj = (const float*)d_in[4];
    float* out = (float*)d_out;
    float* ws = (float*)d_ws;

    // Workspace (floats): q,k,v | qj,kj,vj | xatt | xattj  = 8 * SEG = 100.7 MB
    float* qkv_p = ws;                        // q,k,v   [3][B*H][N][D]
    float* qkv_j = ws + 3 * (size_t)SEG;      // qj,kj,vj
    float* xatt  = ws + 6 * (size_t)SEG;      // [B][N][C]
    float* xattj = ws + 7 * (size_t)SEG;

    // 1) qkv = input @ W_qkv^T (z=0) and input_jvp @ W_qkv^T (z=1), scatter+scale
    gemm_k<0><<<dim3(36, 64, 2), 256, 0, stream>>>(input, inputj, W_qkv, nullptr,
                                                   qkv_p, qkv_j);
    // 2) fused attention + softmax JVP
    attn_k<<<dim3(48, 64, 1), 512, 0, stream>>>(ws, xatt, xattj);
    // 3) projection: out = xatt @ W_proj^T + b ; out_jvp = xattj @ W_proj^T
    gemm_k<1><<<dim3(12, 64, 2), 256, 0, stream>>>(xatt, xattj, W_proj, b_proj,
                                                   out, out + SEG);
}

// Round 5
// 789.448 us; speedup vs baseline: 2.3856x; 2.3856x over previous
//
#include <hip/hip_runtime.h>

// Problem constants (fixed by reference)
constexpr int Bn = 4;
constexpr int Nn = 1024;
constexpr int Cn = 768;
constexpr int Hn = 12;
constexpr int Dn = 64;
constexpr float SCALE_Q = 0.125f;          // D^-0.5
constexpr int SEG = Bn * Nn * Cn;          // 3,145,728
constexpr int HND = Hn * Nn * Dn;          // 786,432
constexpr int NDn = Nn * Dn;               // 65,536

typedef __attribute__((ext_vector_type(8))) short bf16x8;
typedef __attribute__((ext_vector_type(4))) float f32x4;

__device__ __forceinline__ unsigned short f2bf(float f) {
    union { float f; unsigned u; } v; v.f = f;
    unsigned r = v.u + 0x7fffu + ((v.u >> 16) & 1u);   // RNE
    return (unsigned short)(r >> 16);
}
__device__ __forceinline__ float bf2f(unsigned short b) {
    union { unsigned u; float f; } v; v.u = ((unsigned)b) << 16;
    return v.f;
}
__device__ __forceinline__ bf16x8 ldfrag(const unsigned short* base, int boff) {
    return *(const bf16x8*)((const char*)base + boff);
}
#define MFMA(a, b, c) __builtin_amdgcn_mfma_f32_16x16x32_bf16((a), (b), (c), 0, 0, 0)

// ---------------------------------------------------------------------------
// fp32 tiled GEMM (verified round 2): Y = A @ W^T
// MODE 0 (qkv): scatter to q/k/v [B*H][N][D] with SCALE on q; MODE 1 (proj).
// ---------------------------------------------------------------------------
template<int MODE>
__global__ __launch_bounds__(256)
void gemm_k(const float* __restrict__ A0, const float* __restrict__ A1,
            const float* __restrict__ W, const float* __restrict__ bias,
            float* __restrict__ O0, float* __restrict__ O1)
{
    __shared__ float As[16][68];
    __shared__ float Bs[16][68];
    const int tid = threadIdx.x;
    const int z = blockIdx.z;
    const float* __restrict__ A = z ? A1 : A0;
    const int row0 = blockIdx.y << 6;
    const int col0 = blockIdx.x << 6;
    const int lr = tid >> 2;
    const int lk = (tid & 3) << 2;
    const int tm = tid >> 4;
    const int tn = tid & 15;

    const float* __restrict__ Ap = A + (size_t)(row0 + lr) * Cn + lk;
    const float* __restrict__ Wp = W + (size_t)(col0 + lr) * Cn + lk;

    float acc[4][4] = {};

    for (int k0 = 0; k0 < Cn; k0 += 16) {
        const float4 a4 = *(const float4*)(Ap + k0);
        const float4 b4 = *(const float4*)(Wp + k0);
        __syncthreads();
        As[lk + 0][lr] = a4.x; As[lk + 1][lr] = a4.y;
        As[lk + 2][lr] = a4.z; As[lk + 3][lr] = a4.w;
        Bs[lk + 0][lr] = b4.x; Bs[lk + 1][lr] = b4.y;
        Bs[lk + 2][lr] = b4.z; Bs[lk + 3][lr] = b4.w;
        __syncthreads();
#pragma unroll
        for (int kk = 0; kk < 16; ++kk) {
            const float4 av = *(const float4*)&As[kk][tm << 2];
            const float4 bv = *(const float4*)&Bs[kk][tn << 2];
            const float aa[4] = {av.x, av.y, av.z, av.w};
            const float bb[4] = {bv.x, bv.y, bv.z, bv.w};
#pragma unroll
            for (int i = 0; i < 4; ++i)
#pragma unroll
                for (int j = 0; j < 4; ++j)
                    acc[i][j] = fmaf(aa[i], bb[j], acc[i][j]);
        }
    }

    if (MODE == 0) {
        const int t = col0 / Cn;
        const int h = (col0 % Cn) >> 6;
        const float s = (t == 0) ? SCALE_Q : 1.0f;
        float* __restrict__ dst =
            (z ? O1 : O0) + (size_t)t * SEG + (size_t)h * NDn + (tn << 2);
#pragma unroll
        for (int i = 0; i < 4; ++i) {
            const int row = row0 + (tm << 2) + i;
            const int b = row >> 10;
            const int n = row & 1023;
            float4 o;
            o.x = acc[i][0] * s; o.y = acc[i][1] * s;
            o.z = acc[i][2] * s; o.w = acc[i][3] * s;
            *(float4*)(dst + (size_t)b * HND + ((size_t)n << 6)) = o;
        }
    } else {
        float* __restrict__ O = z ? O1 : O0;
        const int colb = col0 + (tn << 2);
        float4 bi = make_float4(0.f, 0.f, 0.f, 0.f);
        if (z == 0) bi = *(const float4*)(bias + colb);
#pragma unroll
        for (int i = 0; i < 4; ++i) {
            const int row = row0 + (tm << 2) + i;
            float4 o;
            o.x = acc[i][0] + bi.x; o.y = acc[i][1] + bi.y;
            o.z = acc[i][2] + bi.z; o.w = acc[i][3] + bi.w;
            *(float4*)(O + (size_t)row * Cn + colb) = o;
        }
    }
}

// ---------------------------------------------------------------------------
// MFMA attention + softmax-JVP, split-bf16 (hi+lo) for fp32-class accuracy.
// Block = (b*h, 64 q rows); 4 waves x 16 q rows; online softmax per lane in
// MFMA C-layout. Per 64-key tile: stage K/KJ (hi,lo) -> S,DM mfma -> softmax
// -> P,P*dm (hi,lo) to wave LDS -> restage V^T/VJ^T -> 3 PV-type mfma prods.
// ---------------------------------------------------------------------------
__global__ __launch_bounds__(256, 2)
void attn_mfma(const float* __restrict__ wsq, float* __restrict__ xatt,
               float* __restrict__ xattj)
{
    // K-phase: 0=Khi 1=Klo 2=KJhi 3=KJlo ; V-phase: 0=Vthi 1=Vtlo 2=VJthi 3=VJtlo
    __shared__ unsigned short sKV[4][64 * 64];     // 32 KB, XOR-swizzled
    __shared__ unsigned short sP[4][4][16 * 64];   // 32 KB, [wave][Phi,Plo,PDhi,PDlo]

    const int tid = threadIdx.x;
    const int l = tid & 63;
    const int w = tid >> 6;          // wave 0..3
    const int h4 = l >> 4;           // 0..3
    const int l15 = l & 15;
    const int sw = (l15 & 7) << 4;   // XOR swizzle term for frag reads

    const int bh = blockIdx.x;       // 0..47
    const int r0 = blockIdx.y << 6;  // 64 q rows per block

    const float* __restrict__ q  = wsq + (size_t)bh * NDn;
    const float* __restrict__ k  = wsq + 1 * (size_t)SEG + (size_t)bh * NDn;
    const float* __restrict__ v  = wsq + 2 * (size_t)SEG + (size_t)bh * NDn;
    const float* __restrict__ qj = wsq + 3 * (size_t)SEG + (size_t)bh * NDn;
    const float* __restrict__ kj = wsq + 4 * (size_t)SEG + (size_t)bh * NDn;
    const float* __restrict__ vj = wsq + 5 * (size_t)SEG + (size_t)bh * NDn;

    // ---- Prologue: Q/QJ fragments (A-layout: m = l15, k = 8*h4 + 32*c + j)
    bf16x8 qhi[2], qlo[2], qjhi[2], qjlo[2];
    {
        const int qrow = r0 + w * 16 + l15;
#pragma unroll
        for (int c = 0; c < 2; ++c) {
            const float* __restrict__ p0 = q + (size_t)qrow * 64 + c * 32 + h4 * 8;
            const float* __restrict__ p1 = qj + (size_t)qrow * 64 + c * 32 + h4 * 8;
            const float4 a = *(const float4*)p0;
            const float4 b = *(const float4*)(p0 + 4);
            const float4 e = *(const float4*)p1;
            const float4 g = *(const float4*)(p1 + 4);
            const float fa[8] = {a.x, a.y, a.z, a.w, b.x, b.y, b.z, b.w};
            const float fb[8] = {e.x, e.y, e.z, e.w, g.x, g.y, g.z, g.w};
#pragma unroll
            for (int j = 0; j < 8; ++j) {
                const unsigned short h0 = f2bf(fa[j]);
                qhi[c][j] = (short)h0;
                qlo[c][j] = (short)f2bf(fa[j] - bf2f(h0));
                const unsigned short h1 = f2bf(fb[j]);
                qjhi[c][j] = (short)h1;
                qjlo[c][j] = (short)f2bf(fb[j] - bf2f(h1));
            }
        }
    }

    // ---- Online-softmax state (component r <-> q = 4*h4 + r)
    f32x4 mold = {-3.0e38f, -3.0e38f, -3.0e38f, -3.0e38f};
    f32x4 l_run = {0.f, 0.f, 0.f, 0.f};
    f32x4 ar_run = {0.f, 0.f, 0.f, 0.f};
    f32x4 ax[4], ac[4], ad[4];   // x, C_jvp, sum(e*dm*v); index = d-subtile
#pragma unroll
    for (int ds = 0; ds < 4; ++ds) {
        ax[ds] = (f32x4){0.f, 0.f, 0.f, 0.f};
        ac[ds] = (f32x4){0.f, 0.f, 0.f, 0.f};
        ad[ds] = (f32x4){0.f, 0.f, 0.f, 0.f};
    }

    for (int jt = 0; jt < Nn; jt += 64) {
        // ---- (a) protect sKV from previous PV reads, then stage K/KJ hi,lo
        __syncthreads();
#pragma unroll
        for (int it = 0; it < 4; ++it) {
            const int idx = it * 256 + tid;
            const int row = idx >> 4, s4 = idx & 15;
            const float4 f = *(const float4*)(k + (size_t)(jt + row) * 64 + s4 * 4);
            const float4 g = *(const float4*)(kj + (size_t)(jt + row) * 64 + s4 * 4);
            const float ff[4] = {f.x, f.y, f.z, f.w};
            const float gg[4] = {g.x, g.y, g.z, g.w};
            ushort4 h0, l0, h1, l1;
#pragma unroll
            for (int i = 0; i < 4; ++i) {
                const unsigned short a = f2bf(ff[i]);
                const unsigned short b = f2bf(gg[i]);
                (&h0.x)[i] = a; (&l0.x)[i] = f2bf(ff[i] - bf2f(a));
                (&h1.x)[i] = b; (&l1.x)[i] = f2bf(gg[i] - bf2f(b));
            }
            const int boff = row * 128 + ((s4 * 8) ^ ((row & 7) << 4));
            *(ushort4*)((char*)sKV[0] + boff) = h0;
            *(ushort4*)((char*)sKV[1] + boff) = l0;
            *(ushort4*)((char*)sKV[2] + boff) = h1;
            *(ushort4*)((char*)sKV[3] + boff) = l1;
        }
        __syncthreads();   // (b)

        // ---- S, DM via split-bf16 MFMA (C-layout: row q=4*h4+r, col key=kt*16+l15)
        f32x4 S[4], DM[4];
#pragma unroll
        for (int kt = 0; kt < 4; ++kt) {
            f32x4 s = {0.f, 0.f, 0.f, 0.f};
            f32x4 dm = {0.f, 0.f, 0.f, 0.f};
#pragma unroll
            for (int c = 0; c < 2; ++c) {
                const int boff = (l15 + (kt << 4)) * 128 + (((h4 << 4) | (c << 6)) ^ sw);
                const bf16x8 khi = ldfrag(sKV[0], boff);
                const bf16x8 klo = ldfrag(sKV[1], boff);
                const bf16x8 jhi = ldfrag(sKV[2], boff);
                const bf16x8 jlo = ldfrag(sKV[3], boff);
                s = MFMA(qhi[c], khi, s);
                s = MFMA(qhi[c], klo, s);
                s = MFMA(qlo[c], khi, s);
                dm = MFMA(qjhi[c], khi, dm);
                dm = MFMA(qjhi[c], klo, dm);
                dm = MFMA(qjlo[c], khi, dm);
                dm = MFMA(qhi[c], jhi, dm);
                dm = MFMA(qhi[c], jlo, dm);
                dm = MFMA(qlo[c], jhi, dm);
            }
            S[kt] = s; DM[kt] = dm;
        }

        // ---- online softmax update (per q: reduce over 4 kt + 16 lanes of quarter)
        f32x4 tmax, mnew, alpha;
#pragma unroll
        for (int r = 0; r < 4; ++r)
            tmax[r] = fmaxf(fmaxf(S[0][r], S[1][r]), fmaxf(S[2][r], S[3][r]));
#pragma unroll
        for (int m = 1; m < 16; m <<= 1)
#pragma unroll
            for (int r = 0; r < 4; ++r)
                tmax[r] = fmaxf(tmax[r], __shfl_xor(tmax[r], m));
#pragma unroll
        for (int r = 0; r < 4; ++r) {
            mnew[r] = fmaxf(mold[r], tmax[r]);
            alpha[r] = __expf(mold[r] - mnew[r]);
            mold[r] = mnew[r];
        }
        f32x4 lsum = {0.f, 0.f, 0.f, 0.f};
        f32x4 arsum = {0.f, 0.f, 0.f, 0.f};
#pragma unroll
        for (int kt = 0; kt < 4; ++kt) {
            const int key = (kt << 4) + l15;
#pragma unroll
            for (int r = 0; r < 4; ++r) {
                const float p = __expf(S[kt][r] - mnew[r]);
                const float pd = p * DM[kt][r];
                lsum[r] += p;
                arsum[r] += pd;
                const int qq = (h4 << 2) + r;
                const int boff = qq * 128 +
                    (((key & 7) << 1) | ((((key >> 3) ^ (qq & 7)) << 4)));
                const unsigned short ph = f2bf(p);
                const unsigned short pdh = f2bf(pd);
                *(unsigned short*)((char*)sP[w][0] + boff) = ph;
                *(unsigned short*)((char*)sP[w][1] + boff) = f2bf(p - bf2f(ph));
                *(unsigned short*)((char*)sP[w][2] + boff) = pdh;
                *(unsigned short*)((char*)sP[w][3] + boff) = f2bf(pd - bf2f(pdh));
            }
        }
#pragma unroll
        for (int r = 0; r < 4; ++r) {
            l_run[r] = l_run[r] * alpha[r] + lsum[r];
            ar_run[r] = ar_run[r] * alpha[r] + arsum[r];
        }
#pragma unroll
        for (int ds = 0; ds < 4; ++ds) {
            ax[ds] *= alpha; ac[ds] *= alpha; ad[ds] *= alpha;
        }

        // ---- (c) done reading K-set; restage sKV with V^T / VJ^T (hi,lo)
        __syncthreads();
        {
            const int j = tid & 63, dgrp = tid >> 6;
#pragma unroll
            for (int dd = 0; dd < 4; ++dd) {
                const int d0 = dgrp * 16 + dd * 4;
                const float4 f = *(const float4*)(v + (size_t)(jt + j) * 64 + d0);
                const float4 g = *(const float4*)(vj + (size_t)(jt + j) * 64 + d0);
                const float ff[4] = {f.x, f.y, f.z, f.w};
                const float gg[4] = {g.x, g.y, g.z, g.w};
#pragma unroll
                for (int i = 0; i < 4; ++i) {
                    const int d = d0 + i;
                    const int boff = d * 128 +
                        (((j & 7) << 1) | ((((j >> 3) ^ (d & 7)) << 4)));
                    const unsigned short a = f2bf(ff[i]);
                    const unsigned short b = f2bf(gg[i]);
                    *(unsigned short*)((char*)sKV[0] + boff) = a;
                    *(unsigned short*)((char*)sKV[1] + boff) = f2bf(ff[i] - bf2f(a));
                    *(unsigned short*)((char*)sKV[2] + boff) = b;
                    *(unsigned short*)((char*)sKV[3] + boff) = f2bf(gg[i] - bf2f(b));
                }
            }
        }
        __syncthreads();   // (d)

        // ---- PV: x += P.V ; xc += P.VJ ; xd += (P*dm).V  (split 3-term each)
#pragma unroll
        for (int kc = 0; kc < 2; ++kc) {
            const int pxo = ((h4 << 4) | (kc << 6)) ^ sw;
            const bf16x8 phi = ldfrag(sP[w][0], l15 * 128 + pxo);
            const bf16x8 plo = ldfrag(sP[w][1], l15 * 128 + pxo);
            const bf16x8 dhi = ldfrag(sP[w][2], l15 * 128 + pxo);
            const bf16x8 dlo = ldfrag(sP[w][3], l15 * 128 + pxo);
#pragma unroll
            for (int ds = 0; ds < 4; ++ds) {
                const int boff = (l15 + (ds << 4)) * 128 + pxo;
                const bf16x8 vhi = ldfrag(sKV[0], boff);
                const bf16x8 vlo = ldfrag(sKV[1], boff);
                const bf16x8 wjh = ldfrag(sKV[2], boff);
                const bf16x8 wjl = ldfrag(sKV[3], boff);
                ax[ds] = MFMA(phi, vhi, ax[ds]);
                ax[ds] = MFMA(phi, vlo, ax[ds]);
                ax[ds] = MFMA(plo, vhi, ax[ds]);
                ac[ds] = MFMA(phi, wjh, ac[ds]);
                ac[ds] = MFMA(phi, wjl, ac[ds]);
                ac[ds] = MFMA(plo, wjh, ac[ds]);
                ad[ds] = MFMA(dhi, vhi, ad[ds]);
                ad[ds] = MFMA(dhi, vlo, ad[ds]);
                ad[ds] = MFMA(dlo, vhi, ad[ds]);
            }
        }
    }

    // ---- Epilogue: reduce l, ar across quarter; normalize; JVP correction; store
#pragma unroll
    for (int m = 1; m < 16; m <<= 1)
#pragma unroll
        for (int r = 0; r < 4; ++r) {
            l_run[r] += __shfl_xor(l_run[r], m);
            ar_run[r] += __shfl_xor(ar_run[r], m);
        }
    const int b = bh / Hn;
    const int hh = bh - b * Hn;
#pragma unroll
    for (int r = 0; r < 4; ++r) {
        const int qg = r0 + w * 16 + (h4 << 2) + r;
        const float invl = 1.0f / l_run[r];
        const float rowv = ar_run[r] * invl;
        const size_t base = ((size_t)(b * Nn + qg)) * Cn + hh * Dn + l15;
#pragma unroll
        for (int ds = 0; ds < 4; ++ds) {
            const float x = ax[ds][r] * invl;
            const float xjv = fmaf(-rowv, x, (ad[ds][r] + ac[ds][r]) * invl);
            xatt[base + ds * 16] = x;
            xattj[base + ds * 16] = xjv;
        }
    }
}

extern "C" void kernel_launch(void* const* d_in, const int* in_sizes, int n_in,
                              void* d_out, int out_size, void* d_ws, size_t ws_size,
                              hipStream_t stream)
{
    const float* input  = (const float*)d_in[0];
    const float* inputj = (const float*)d_in[1];
    const float* W_qkv  = (const float*)d_in[2];
    const float* W_proj = (const float*)d_in[3];
    const float* b_proj = (const float*)d_in[4];
    float* out = (float*)d_out;
    float* ws = (float*)d_ws;

    float* qkv_p = ws;                        // q,k,v   [3][B*H][N][D]
    float* qkv_j = ws + 3 * (size_t)SEG;      // qj,kj,vj
    float* xatt  = ws + 6 * (size_t)SEG;      // [B][N][C]
    float* xattj = ws + 7 * (size_t)SEG;

    gemm_k<0><<<dim3(36, 64, 2), 256, 0, stream>>>(input, inputj, W_qkv, nullptr,
                                                   qkv_p, qkv_j);
    attn_mfma<<<dim3(48, 16), 256, 0, stream>>>(ws, xatt, xattj);
    gemm_k<1><<<dim3(12, 64, 2), 256, 0, stream>>>(xatt, xattj, W_proj, b_proj,
                                                   out, out + SEG);
}

// Round 6
// 400.859 us; speedup vs baseline: 4.6982x; 1.9694x over previous
//
#include <hip/hip_runtime.h>

// Problem constants (fixed by reference)
constexpr int Bn = 4;
constexpr int Nn = 1024;
constexpr int Cn = 768;
constexpr int Hn = 12;
constexpr int Dn = 64;
constexpr float SCALE_Q = 0.125f;          // D^-0.5
constexpr int SEG = Bn * Nn * Cn;          // 3,145,728 elements per tensor
constexpr int HND = Hn * Nn * Dn;
constexpr int NDn = Nn * Dn;               // 65,536

typedef __attribute__((ext_vector_type(8))) short bf16x8;
typedef __attribute__((ext_vector_type(4))) float f32x4;

__device__ __forceinline__ unsigned short f2bf(float f) {
    union { float f; unsigned u; } v; v.f = f;
    unsigned r = v.u + 0x7fffu + ((v.u >> 16) & 1u);   // RNE
    return (unsigned short)(r >> 16);
}
__device__ __forceinline__ float bf2f(unsigned short b) {
    union { unsigned u; float f; } v; v.u = ((unsigned)b) << 16;
    return v.f;
}
__device__ __forceinline__ bf16x8 ldfrag(const unsigned short* base, int boff) {
    return *(const bf16x8*)((const char*)base + boff);
}
#define MFMA(a, b, c) __builtin_amdgcn_mfma_f32_16x16x32_bf16((a), (b), (c), 0, 0, 0)

// ---------------------------------------------------------------------------
// Workspace layout (ushort units), total 16*SEG ushorts = 100.66 MB:
//  region A (off 0)      : [INh0|INl0|INh1|INl1]  -> reused as [xh|xl|xjh|xjl]
//  region B (off 4*SEG)  : qkv t2=0..5 (q,k,v,qj,kj,vj), hi at (2*t2)*SEG, lo +SEG
// ---------------------------------------------------------------------------

// fp32 -> (hi,lo) bf16 split of input / input_jvp.
__global__ __launch_bounds__(256)
void conv_k(const float* __restrict__ a0, const float* __restrict__ a1,
            unsigned short* __restrict__ dst)
{
    const int P = SEG / 4;                       // float4 slots per array
    const int j = blockIdx.x * 256 + threadIdx.x;
    const int arr = j / P;
    const int i = (j - arr * P) * 4;
    const float* __restrict__ src = arr ? a1 : a0;
    const float4 f = *(const float4*)(src + i);
    const float ff[4] = {f.x, f.y, f.z, f.w};
    ushort4 h, lo;
#pragma unroll
    for (int t = 0; t < 4; ++t) {
        const unsigned short hv = f2bf(ff[t]);
        (&h.x)[t] = hv;
        (&lo.x)[t] = f2bf(ff[t] - bf2f(hv));
    }
    *(ushort4*)(dst + (size_t)(2 * arr) * SEG + i) = h;
    *(ushort4*)(dst + (size_t)(2 * arr + 1) * SEG + i) = lo;
}

// ---------------------------------------------------------------------------
// Split-bf16 MFMA GEMM: Y = A @ W^T. A pre-split (hi/lo bf16), W fp32
// (converted during LDS staging). 128x128 tile, BK=64, 4 waves, 64KB LDS.
// MODE 0: scatter q/k/v to region B as hi/lo bf16 (SCALE on q third).
// MODE 1: out[z*SEG + row*768 + col] = acc (+bias for z==0).
// ---------------------------------------------------------------------------
template<int MODE>
__global__ __launch_bounds__(256, 2)
void gemm_mfma(const unsigned short* __restrict__ Abase,
               const float* __restrict__ W, const float* __restrict__ bias,
               unsigned short* __restrict__ qkv, float* __restrict__ out)
{
    __shared__ unsigned short sAh[128 * 64];
    __shared__ unsigned short sAl[128 * 64];
    __shared__ unsigned short sBh[128 * 64];
    __shared__ unsigned short sBl[128 * 64];

    const int tid = threadIdx.x;
    const int z = blockIdx.z;
    const int row0 = blockIdx.y << 7;
    const int col0 = blockIdx.x << 7;
    const int l = tid & 63, w = tid >> 6;
    const int wr = w >> 1, wc = w & 1;            // 64x64 quadrant per wave
    const int h4 = l >> 4, l15 = l & 15;
    const int sw = (l15 & 7) << 4;

    const unsigned short* __restrict__ Ah = Abase + (size_t)(2 * z) * SEG;
    const unsigned short* __restrict__ Al = Abase + (size_t)(2 * z + 1) * SEG;

    f32x4 acc[4][4];
#pragma unroll
    for (int m = 0; m < 4; ++m)
#pragma unroll
        for (int n = 0; n < 4; ++n)
            acc[m][n] = (f32x4){0.f, 0.f, 0.f, 0.f};

    for (int k0 = 0; k0 < Cn; k0 += 64) {
        __syncthreads();
        // stage A (pre-split): 128 rows x 8 ushort8-groups
#pragma unroll
        for (int it = 0; it < 4; ++it) {
            const int idx = it * 256 + tid;
            const int row = idx >> 3, s = idx & 7;
            const size_t go = (size_t)(row0 + row) * Cn + k0 + 8 * s;
            const int boff = row * 128 + ((s ^ (row & 7)) << 4);
            *(bf16x8*)((char*)sAh + boff) = *(const bf16x8*)(Ah + go);
            *(bf16x8*)((char*)sAl + boff) = *(const bf16x8*)(Al + go);
        }
        // stage B from fp32 W with conversion: 128 rows x 16 float4-slots
#pragma unroll
        for (int it = 0; it < 8; ++it) {
            const int idx = it * 256 + tid;
            const int row = idx >> 4, s4 = idx & 15;
            const float4 f = *(const float4*)(W + (size_t)(col0 + row) * Cn + k0 + 4 * s4);
            const float ff[4] = {f.x, f.y, f.z, f.w};
            ushort4 h, lo;
#pragma unroll
            for (int t = 0; t < 4; ++t) {
                const unsigned short hv = f2bf(ff[t]);
                (&h.x)[t] = hv;
                (&lo.x)[t] = f2bf(ff[t] - bf2f(hv));
            }
            const int boff = row * 128 + (((s4 >> 1) ^ (row & 7)) << 4) + ((s4 & 1) << 3);
            *(ushort4*)((char*)sBh + boff) = h;
            *(ushort4*)((char*)sBl + boff) = lo;
        }
        __syncthreads();
#pragma unroll
        for (int c = 0; c < 2; ++c) {
            bf16x8 ah[4], al[4], bh[4], bl[4];
#pragma unroll
            for (int m = 0; m < 4; ++m) {
                const int boff = (64 * wr + 16 * m + l15) * 128 + ((((c << 2) | h4) << 4) ^ sw);
                ah[m] = ldfrag(sAh, boff);
                al[m] = ldfrag(sAl, boff);
            }
#pragma unroll
            for (int n = 0; n < 4; ++n) {
                const int boff = (64 * wc + 16 * n + l15) * 128 + ((((c << 2) | h4) << 4) ^ sw);
                bh[n] = ldfrag(sBh, boff);
                bl[n] = ldfrag(sBl, boff);
            }
#pragma unroll
            for (int m = 0; m < 4; ++m)
#pragma unroll
                for (int n = 0; n < 4; ++n) {
                    acc[m][n] = MFMA(ah[m], bh[n], acc[m][n]);
                    acc[m][n] = MFMA(ah[m], bl[n], acc[m][n]);
                    acc[m][n] = MFMA(al[m], bh[n], acc[m][n]);
                }
        }
    }

    if (MODE == 0) {
#pragma unroll
        for (int n = 0; n < 4; ++n) {
            const int colb = col0 + 64 * wc + 16 * n;   // 16-col frag within one (t,h)
            const int t = colb / Cn;
            const int rem = colb - t * Cn;
            const int hh = rem >> 6;
            const int d = (rem & 63) + l15;
            const float sc = (t == 0) ? SCALE_Q : 1.0f;
            const int t2 = t + 3 * z;
            unsigned short* __restrict__ dh = qkv + (size_t)(2 * t2) * SEG;
            unsigned short* __restrict__ dl = dh + SEG;
#pragma unroll
            for (int m = 0; m < 4; ++m)
#pragma unroll
                for (int r = 0; r < 4; ++r) {
                    const int row = row0 + 64 * wr + 16 * m + 4 * h4 + r;
                    const int b = row >> 10, nq = row & 1023;
                    const size_t ad = (size_t)(b * Hn + hh) * NDn + nq * 64 + d;
                    const float vv = acc[m][n][r] * sc;
                    const unsigned short hv = f2bf(vv);
                    dh[ad] = hv;
                    dl[ad] = f2bf(vv - bf2f(hv));
                }
        }
    } else {
#pragma unroll
        for (int n = 0; n < 4; ++n) {
            const int col = col0 + 64 * wc + 16 * n + l15;
            const float bi = (z == 0) ? bias[col] : 0.0f;
#pragma unroll
            for (int m = 0; m < 4; ++m)
#pragma unroll
                for (int r = 0; r < 4; ++r) {
                    const int row = row0 + 64 * wr + 16 * m + 4 * h4 + r;
                    out[(size_t)z * SEG + (size_t)row * Cn + col] = acc[m][n][r] + bi;
                }
        }
    }
}

// ---------------------------------------------------------------------------
// MFMA attention + softmax-JVP (verified structure). Inputs pre-split hi/lo
// bf16 -> staging is pure copy (no conversion VALU). Outputs x/xj as hi/lo.
// ---------------------------------------------------------------------------
__global__ __launch_bounds__(256, 2)
void attn_mfma(unsigned short* __restrict__ wsu)
{
    __shared__ unsigned short sKV[4][64 * 64];     // 32 KB, XOR-swizzled
    __shared__ unsigned short sP[4][4][16 * 64];   // 32 KB, wave-private

    const int tid = threadIdx.x;
    const int l = tid & 63;
    const int w = tid >> 6;
    const int h4 = l >> 4;
    const int l15 = l & 15;
    const int sw = (l15 & 7) << 4;

    const int bh = blockIdx.x;
    const int r0 = blockIdx.y << 6;

    const unsigned short* __restrict__ Bq = wsu + 4 * (size_t)SEG + (size_t)bh * NDn;
    const unsigned short* __restrict__ qh = Bq;                    // t2=0
    const unsigned short* __restrict__ kh = Bq + 2 * (size_t)SEG;  // t2=1
    const unsigned short* __restrict__ vh = Bq + 4 * (size_t)SEG;  // t2=2
    const unsigned short* __restrict__ qjh = Bq + 6 * (size_t)SEG; // t2=3
    const unsigned short* __restrict__ kjh = Bq + 8 * (size_t)SEG; // t2=4
    const unsigned short* __restrict__ vjh = Bq + 10 * (size_t)SEG;// t2=5
    // lo of each tensor = hi + SEG

    // ---- Prologue: Q/QJ fragments straight from pre-split global
    bf16x8 qhi[2], qlo[2], qjhi[2], qjlo[2];
    {
        const int qrow = r0 + w * 16 + l15;
#pragma unroll
        for (int c = 0; c < 2; ++c) {
            const size_t o = (size_t)qrow * 64 + c * 32 + h4 * 8;
            qhi[c] = *(const bf16x8*)(qh + o);
            qlo[c] = *(const bf16x8*)(qh + SEG + o);
            qjhi[c] = *(const bf16x8*)(qjh + o);
            qjlo[c] = *(const bf16x8*)(qjh + SEG + o);
        }
    }

    f32x4 mold = {-3.0e38f, -3.0e38f, -3.0e38f, -3.0e38f};
    f32x4 l_run = {0.f, 0.f, 0.f, 0.f};
    f32x4 ar_run = {0.f, 0.f, 0.f, 0.f};
    f32x4 ax[4], ac[4], ad[4];
#pragma unroll
    for (int ds = 0; ds < 4; ++ds) {
        ax[ds] = (f32x4){0.f, 0.f, 0.f, 0.f};
        ac[ds] = (f32x4){0.f, 0.f, 0.f, 0.f};
        ad[ds] = (f32x4){0.f, 0.f, 0.f, 0.f};
    }

    for (int jt = 0; jt < Nn; jt += 64) {
        // ---- (a) stage K/KJ hi,lo (pure 16B copies)
        __syncthreads();
#pragma unroll
        for (int it = 0; it < 2; ++it) {
            const int idx = it * 256 + tid;
            const int row = idx >> 3, s = idx & 7;
            const size_t go = (size_t)(jt + row) * 64 + 8 * s;
            const int boff = row * 128 + ((s ^ (row & 7)) << 4);
            *(bf16x8*)((char*)sKV[0] + boff) = *(const bf16x8*)(kh + go);
            *(bf16x8*)((char*)sKV[1] + boff) = *(const bf16x8*)(kh + SEG + go);
            *(bf16x8*)((char*)sKV[2] + boff) = *(const bf16x8*)(kjh + go);
            *(bf16x8*)((char*)sKV[3] + boff) = *(const bf16x8*)(kjh + SEG + go);
        }
        __syncthreads();   // (b)

        // ---- S, DM via split-bf16 MFMA
        f32x4 S[4], DM[4];
#pragma unroll
        for (int kt = 0; kt < 4; ++kt) {
            f32x4 s = {0.f, 0.f, 0.f, 0.f};
            f32x4 dm = {0.f, 0.f, 0.f, 0.f};
#pragma unroll
            for (int c = 0; c < 2; ++c) {
                const int boff = (l15 + (kt << 4)) * 128 + (((h4 << 4) | (c << 6)) ^ sw);
                const bf16x8 khi = ldfrag(sKV[0], boff);
                const bf16x8 klo = ldfrag(sKV[1], boff);
                const bf16x8 jhi = ldfrag(sKV[2], boff);
                const bf16x8 jlo = ldfrag(sKV[3], boff);
                s = MFMA(qhi[c], khi, s);
                s = MFMA(qhi[c], klo, s);
                s = MFMA(qlo[c], khi, s);
                dm = MFMA(qjhi[c], khi, dm);
                dm = MFMA(qjhi[c], klo, dm);
                dm = MFMA(qjlo[c], khi, dm);
                dm = MFMA(qhi[c], jhi, dm);
                dm = MFMA(qhi[c], jlo, dm);
                dm = MFMA(qlo[c], jhi, dm);
            }
            S[kt] = s; DM[kt] = dm;
        }

        // ---- online softmax update
        f32x4 tmax, mnew, alpha;
#pragma unroll
        for (int r = 0; r < 4; ++r)
            tmax[r] = fmaxf(fmaxf(S[0][r], S[1][r]), fmaxf(S[2][r], S[3][r]));
#pragma unroll
        for (int m = 1; m < 16; m <<= 1)
#pragma unroll
            for (int r = 0; r < 4; ++r)
                tmax[r] = fmaxf(tmax[r], __shfl_xor(tmax[r], m));
#pragma unroll
        for (int r = 0; r < 4; ++r) {
            mnew[r] = fmaxf(mold[r], tmax[r]);
            alpha[r] = __expf(mold[r] - mnew[r]);
            mold[r] = mnew[r];
        }
        f32x4 lsum = {0.f, 0.f, 0.f, 0.f};
        f32x4 arsum = {0.f, 0.f, 0.f, 0.f};
#pragma unroll
        for (int kt = 0; kt < 4; ++kt) {
            const int key = (kt << 4) + l15;
#pragma unroll
            for (int r = 0; r < 4; ++r) {
                const float p = __expf(S[kt][r] - mnew[r]);
                const float pd = p * DM[kt][r];
                lsum[r] += p;
                arsum[r] += pd;
                const int qq = (h4 << 2) + r;
                const int boff = qq * 128 +
                    (((key & 7) << 1) | ((((key >> 3) ^ (qq & 7)) << 4)));
                const unsigned short ph = f2bf(p);
                const unsigned short pdh = f2bf(pd);
                *(unsigned short*)((char*)sP[w][0] + boff) = ph;
                *(unsigned short*)((char*)sP[w][1] + boff) = f2bf(p - bf2f(ph));
                *(unsigned short*)((char*)sP[w][2] + boff) = pdh;
                *(unsigned short*)((char*)sP[w][3] + boff) = f2bf(pd - bf2f(pdh));
            }
        }
#pragma unroll
        for (int r = 0; r < 4; ++r) {
            l_run[r] = l_run[r] * alpha[r] + lsum[r];
            ar_run[r] = ar_run[r] * alpha[r] + arsum[r];
        }
#pragma unroll
        for (int ds = 0; ds < 4; ++ds) {
            ax[ds] *= alpha; ac[ds] *= alpha; ad[ds] *= alpha;
        }

        // ---- (c) restage sKV with V^T / VJ^T (pre-split, scalar transpose)
        __syncthreads();
        {
            const int j = tid & 63, dgrp = tid >> 6;
#pragma unroll
            for (int dd = 0; dd < 4; ++dd) {
                const int d0 = dgrp * 16 + dd * 4;
                const size_t go = (size_t)(jt + j) * 64 + d0;
                const ushort4 a = *(const ushort4*)(vh + go);
                const ushort4 b = *(const ushort4*)(vh + SEG + go);
                const ushort4 c = *(const ushort4*)(vjh + go);
                const ushort4 e = *(const ushort4*)(vjh + SEG + go);
#pragma unroll
                for (int i = 0; i < 4; ++i) {
                    const int d = d0 + i;
                    const int boff = d * 128 +
                        (((j & 7) << 1) | ((((j >> 3) ^ (d & 7)) << 4)));
                    *(unsigned short*)((char*)sKV[0] + boff) = (&a.x)[i];
                    *(unsigned short*)((char*)sKV[1] + boff) = (&b.x)[i];
                    *(unsigned short*)((char*)sKV[2] + boff) = (&c.x)[i];
                    *(unsigned short*)((char*)sKV[3] + boff) = (&e.x)[i];
                }
            }
        }
        __syncthreads();   // (d)

        // ---- PV: x += P.V ; xc += P.VJ ; xd += (P*dm).V
#pragma unroll
        for (int kc = 0; kc < 2; ++kc) {
            const int pxo = ((h4 << 4) | (kc << 6)) ^ sw;
            const bf16x8 phi = ldfrag(sP[w][0], l15 * 128 + pxo);
            const bf16x8 plo = ldfrag(sP[w][1], l15 * 128 + pxo);
            const bf16x8 dhi = ldfrag(sP[w][2], l15 * 128 + pxo);
            const bf16x8 dlo = ldfrag(sP[w][3], l15 * 128 + pxo);
#pragma unroll
            for (int ds = 0; ds < 4; ++ds) {
                const int boff = (l15 + (ds << 4)) * 128 + pxo;
                const bf16x8 vhi = ldfrag(sKV[0], boff);
                const bf16x8 vlo = ldfrag(sKV[1], boff);
                const bf16x8 wjh = ldfrag(sKV[2], boff);
                const bf16x8 wjl = ldfrag(sKV[3], boff);
                ax[ds] = MFMA(phi, vhi, ax[ds]);
                ax[ds] = MFMA(phi, vlo, ax[ds]);
                ax[ds] = MFMA(plo, vhi, ax[ds]);
                ac[ds] = MFMA(phi, wjh, ac[ds]);
                ac[ds] = MFMA(phi, wjl, ac[ds]);
                ac[ds] = MFMA(plo, wjh, ac[ds]);
                ad[ds] = MFMA(dhi, vhi, ad[ds]);
                ad[ds] = MFMA(dhi, vlo, ad[ds]);
                ad[ds] = MFMA(dlo, vhi, ad[ds]);
            }
        }
    }

    // ---- Epilogue: normalize, JVP correction, store x/xj as hi/lo bf16
#pragma unroll
    for (int m = 1; m < 16; m <<= 1)
#pragma unroll
        for (int r = 0; r < 4; ++r) {
            l_run[r] += __shfl_xor(l_run[r], m);
            ar_run[r] += __shfl_xor(ar_run[r], m);
        }
    const int b = bh / Hn;
    const int hh = bh - b * Hn;
    unsigned short* __restrict__ xh = wsu;                     // region A
    unsigned short* __restrict__ xl = wsu + (size_t)SEG;
    unsigned short* __restrict__ xjh = wsu + 2 * (size_t)SEG;
    unsigned short* __restrict__ xjl = wsu + 3 * (size_t)SEG;
#pragma unroll
    for (int r = 0; r < 4; ++r) {
        const int qg = r0 + w * 16 + (h4 << 2) + r;
        const float invl = 1.0f / l_run[r];
        const float rowv = ar_run[r] * invl;
        const size_t base = ((size_t)(b * Nn + qg)) * Cn + hh * Dn + l15;
#pragma unroll
        for (int ds = 0; ds < 4; ++ds) {
            const float x = ax[ds][r] * invl;
            const float xjv = fmaf(-rowv, x, (ad[ds][r] + ac[ds][r]) * invl);
            const size_t ad2 = base + ds * 16;
            const unsigned short h0 = f2bf(x);
            xh[ad2] = h0;
            xl[ad2] = f2bf(x - bf2f(h0));
            const unsigned short h1 = f2bf(xjv);
            xjh[ad2] = h1;
            xjl[ad2] = f2bf(xjv - bf2f(h1));
        }
    }
}

extern "C" void kernel_launch(void* const* d_in, const int* in_sizes, int n_in,
                              void* d_out, int out_size, void* d_ws, size_t ws_size,
                              hipStream_t stream)
{
    const float* input  = (const float*)d_in[0];
    const float* inputj = (const float*)d_in[1];
    const float* W_qkv  = (const float*)d_in[2];
    const float* W_proj = (const float*)d_in[3];
    const float* b_proj = (const float*)d_in[4];
    float* out = (float*)d_out;
    unsigned short* wsu = (unsigned short*)d_ws;     // 16*SEG ushorts total
    unsigned short* regA = wsu;                      // IN splits -> x splits
    unsigned short* regB = wsu + 4 * (size_t)SEG;    // qkv splits (12 segs)

    // 1) split input / input_jvp into hi/lo bf16
    conv_k<<<2 * (SEG / 4) / 256, 256, 0, stream>>>(input, inputj, regA);
    // 2) qkv = IN @ W_qkv^T  (MFMA, scatter hi/lo + scale q)
    gemm_mfma<0><<<dim3(18, 32, 2), 256, 0, stream>>>(regA, W_qkv, nullptr,
                                                      regB, nullptr);
    // 3) fused attention + softmax JVP (writes x/xj hi/lo into region A)
    attn_mfma<<<dim3(48, 16), 256, 0, stream>>>(wsu);
    // 4) out = x @ W_proj^T (+bias on primal)
    gemm_mfma<1><<<dim3(6, 32, 2), 256, 0, stream>>>(regA, W_proj, b_proj,
                                                     nullptr, out);
}

// Round 7
// 398.524 us; speedup vs baseline: 4.7257x; 1.0059x over previous
//
#include <hip/hip_runtime.h>

// Problem constants (fixed by reference)
constexpr int Bn = 4;
constexpr int Nn = 1024;
constexpr int Cn = 768;
constexpr int Hn = 12;
constexpr int Dn = 64;
constexpr float SCALE_Q = 0.125f;          // D^-0.5
constexpr int SEG = Bn * Nn * Cn;          // 3,145,728 elements per tensor
constexpr int NDn = Nn * Dn;               // 65,536
constexpr int WQ_ELE = 3 * Cn * Cn;        // 1,769,472
constexpr int WP_ELE = Cn * Cn;            // 589,824

typedef __attribute__((ext_vector_type(8))) short bf16x8;
typedef __attribute__((ext_vector_type(4))) float f32x4;

__device__ __forceinline__ unsigned short f2bf(float f) {
    union { float f; unsigned u; } v; v.f = f;
    unsigned r = v.u + 0x7fffu + ((v.u >> 16) & 1u);   // RNE
    return (unsigned short)(r >> 16);
}
__device__ __forceinline__ float bf2f(unsigned short b) {
    union { unsigned u; float f; } v; v.u = ((unsigned)b) << 16;
    return v.f;
}
__device__ __forceinline__ bf16x8 ldfrag(const unsigned short* base, int boff) {
    return *(const bf16x8*)((const char*)base + boff);
}
#define MFMA(a, b, c) __builtin_amdgcn_mfma_f32_16x16x32_bf16((a), (b), (c), 0, 0, 0)

// ---------------------------------------------------------------------------
// Workspace layout (ushort units), total 16*SEG ushorts:
//  region A (off 0)      : [INh0|INl0|INh1|INl1] -> reused as [xh|xl|xjh|xjl]
//  region B (off 4*SEG)  : qkv t2=0..5, hi at (2*t2)*SEG, lo +SEG.
//                          v/vj (t2=2,5) stored TRANSPOSED [bh][d][n].
//                          After attn, head of region B reused for W_proj split.
//  d_out: used as scratch for W_qkv hi/lo split until final GEMM overwrites it.
// ---------------------------------------------------------------------------

// fp32 -> (hi,lo) bf16 split of input / input_jvp.
__global__ __launch_bounds__(256)
void conv_k(const float* __restrict__ a0, const float* __restrict__ a1,
            unsigned short* __restrict__ dst)
{
    const int P = SEG / 4;
    const int j = blockIdx.x * 256 + threadIdx.x;
    const int arr = j / P;
    const int i = (j - arr * P) * 4;
    const float* __restrict__ src = arr ? a1 : a0;
    const float4 f = *(const float4*)(src + i);
    const float ff[4] = {f.x, f.y, f.z, f.w};
    ushort4 h, lo;
#pragma unroll
    for (int t = 0; t < 4; ++t) {
        const unsigned short hv = f2bf(ff[t]);
        (&h.x)[t] = hv;
        (&lo.x)[t] = f2bf(ff[t] - bf2f(hv));
    }
    *(ushort4*)(dst + (size_t)(2 * arr) * SEG + i) = h;
    *(ushort4*)(dst + (size_t)(2 * arr + 1) * SEG + i) = lo;
}

// fp32 -> (hi,lo) bf16 split, flat array (for weights).
__global__ __launch_bounds__(256)
void conv_w(const float* __restrict__ src, unsigned short* __restrict__ dh,
            unsigned short* __restrict__ dl)
{
    const int i = (blockIdx.x * 256 + threadIdx.x) * 4;
    const float4 f = *(const float4*)(src + i);
    const float ff[4] = {f.x, f.y, f.z, f.w};
    ushort4 h, lo;
#pragma unroll
    for (int t = 0; t < 4; ++t) {
        const unsigned short hv = f2bf(ff[t]);
        (&h.x)[t] = hv;
        (&lo.x)[t] = f2bf(ff[t] - bf2f(hv));
    }
    *(ushort4*)(dh + i) = h;
    *(ushort4*)(dl + i) = lo;
}

// ---------------------------------------------------------------------------
// Split-bf16 MFMA GEMM: Y = A @ W^T. A and W both pre-split (hi/lo bf16).
// 128x128 tile, BK=64, 4 waves. T14: next tile loaded to regs during MFMA.
// MODE 0: scatter q/k/v to region B (SCALE on q; v/vj transposed [d][n]).
// MODE 1: out[z*SEG + row*768 + col] = acc (+bias for z==0).
// ---------------------------------------------------------------------------
template<int MODE>
__global__ __launch_bounds__(256, 2)
void gemm_mfma(const unsigned short* __restrict__ Abase,
               const unsigned short* __restrict__ Wh,
               const unsigned short* __restrict__ Wl,
               const float* __restrict__ bias,
               unsigned short* __restrict__ qkv, float* __restrict__ out)
{
    __shared__ unsigned short sAh[128 * 64];
    __shared__ unsigned short sAl[128 * 64];
    __shared__ unsigned short sBh[128 * 64];
    __shared__ unsigned short sBl[128 * 64];

    const int tid = threadIdx.x;
    const int z = blockIdx.z;
    const int row0 = blockIdx.y << 7;
    const int col0 = blockIdx.x << 7;
    const int l = tid & 63, w = tid >> 6;
    const int wr = w >> 1, wc = w & 1;
    const int h4 = l >> 4, l15 = l & 15;
    const int sw = (l15 & 7) << 4;
    const int srow = tid >> 3;            // 0..31, covers rows srow+32*it
    const int ss = tid & 7;

    const unsigned short* __restrict__ Ah = Abase + (size_t)(2 * z) * SEG;
    const unsigned short* __restrict__ Al = Abase + (size_t)(2 * z + 1) * SEG;

    f32x4 acc[4][4];
#pragma unroll
    for (int m = 0; m < 4; ++m)
#pragma unroll
        for (int n = 0; n < 4; ++n)
            acc[m][n] = (f32x4){0.f, 0.f, 0.f, 0.f};

    bf16x8 pAh[4], pAl[4], pBh[4], pBl[4];

#define G_LOADT(K0_) {                                                        \
    _Pragma("unroll")                                                         \
    for (int it = 0; it < 4; ++it) {                                          \
        const int row = srow + 32 * it;                                       \
        const size_t goA = (size_t)(row0 + row) * Cn + (K0_) + 8 * ss;        \
        const size_t goB = (size_t)(col0 + row) * Cn + (K0_) + 8 * ss;        \
        pAh[it] = *(const bf16x8*)(Ah + goA);                                 \
        pAl[it] = *(const bf16x8*)(Al + goA);                                 \
        pBh[it] = *(const bf16x8*)(Wh + goB);                                 \
        pBl[it] = *(const bf16x8*)(Wl + goB);                                 \
    } }

    G_LOADT(0);

    for (int k0 = 0; k0 < Cn; k0 += 64) {
        __syncthreads();
#pragma unroll
        for (int it = 0; it < 4; ++it) {
            const int row = srow + 32 * it;
            const int boff = row * 128 + ((ss ^ (row & 7)) << 4);
            *(bf16x8*)((char*)sAh + boff) = pAh[it];
            *(bf16x8*)((char*)sAl + boff) = pAl[it];
            *(bf16x8*)((char*)sBh + boff) = pBh[it];
            *(bf16x8*)((char*)sBl + boff) = pBl[it];
        }
        const int kn = (k0 + 64 < Cn) ? k0 + 64 : 0;
        G_LOADT(kn);                       // T14: hide under MFMA phase
        __syncthreads();
#pragma unroll
        for (int c = 0; c < 2; ++c) {
            bf16x8 ah[4], al[4], bh[4], bl[4];
#pragma unroll
            for (int m = 0; m < 4; ++m) {
                const int boff = (64 * wr + 16 * m + l15) * 128 + ((((c << 2) | h4) << 4) ^ sw);
                ah[m] = ldfrag(sAh, boff);
                al[m] = ldfrag(sAl, boff);
            }
#pragma unroll
            for (int n = 0; n < 4; ++n) {
                const int boff = (64 * wc + 16 * n + l15) * 128 + ((((c << 2) | h4) << 4) ^ sw);
                bh[n] = ldfrag(sBh, boff);
                bl[n] = ldfrag(sBl, boff);
            }
#pragma unroll
            for (int m = 0; m < 4; ++m)
#pragma unroll
                for (int n = 0; n < 4; ++n) {
                    acc[m][n] = MFMA(ah[m], bh[n], acc[m][n]);
                    acc[m][n] = MFMA(ah[m], bl[n], acc[m][n]);
                    acc[m][n] = MFMA(al[m], bh[n], acc[m][n]);
                }
        }
    }

    if (MODE == 0) {
#pragma unroll
        for (int n = 0; n < 4; ++n) {
            const int colb = col0 + 64 * wc + 16 * n;
            const int t = colb / Cn;
            const int rem = colb - t * Cn;
            const int hh = rem >> 6;
            const int d = (rem & 63) + l15;
            const float sc = (t == 0) ? SCALE_Q : 1.0f;
            const int t2 = t + 3 * z;
            unsigned short* __restrict__ dh = qkv + (size_t)(2 * t2) * SEG;
            unsigned short* __restrict__ dl = dh + SEG;
#pragma unroll
            for (int m = 0; m < 4; ++m)
#pragma unroll
                for (int r = 0; r < 4; ++r) {
                    const int row = row0 + 64 * wr + 16 * m + 4 * h4 + r;
                    const int b = row >> 10, nq = row & 1023;
                    const size_t ad = (size_t)(b * Hn + hh) * NDn +
                        (t == 2 ? (size_t)d * Nn + nq     // v/vj transposed [d][n]
                                : (size_t)nq * 64 + d);
                    const float vv = acc[m][n][r] * sc;
                    const unsigned short hv = f2bf(vv);
                    dh[ad] = hv;
                    dl[ad] = f2bf(vv - bf2f(hv));
                }
        }
    } else {
#pragma unroll
        for (int n = 0; n < 4; ++n) {
            const int col = col0 + 64 * wc + 16 * n + l15;
            const float bi = (z == 0) ? bias[col] : 0.0f;
#pragma unroll
            for (int m = 0; m < 4; ++m)
#pragma unroll
                for (int r = 0; r < 4; ++r) {
                    const int row = row0 + 64 * wr + 16 * m + 4 * h4 + r;
                    out[(size_t)z * SEG + (size_t)row * Cn + col] = acc[m][n][r] + bi;
                }
        }
    }
}

// ---------------------------------------------------------------------------
// MFMA attention + softmax-JVP (verified structure). K row-major, V pre-
// transposed [d][n] in global. T14: K/V global loads issued during compute,
// LDS writes after barrier are pure b128 reg copies. T5 setprio on MFMA.
// ---------------------------------------------------------------------------
__global__ __launch_bounds__(256, 2)
void attn_mfma(unsigned short* __restrict__ wsu)
{
    __shared__ unsigned short sKV[4][64 * 64];     // 32 KB, XOR-swizzled
    __shared__ unsigned short sP[4][4][16 * 64];   // 32 KB, wave-private

    const int tid = threadIdx.x;
    const int l = tid & 63;
    const int w = tid >> 6;
    const int h4 = l >> 4;
    const int l15 = l & 15;
    const int sw = (l15 & 7) << 4;
    const int rA = tid >> 3;          // staging row 0..31 (and rA+32)
    const int ss = tid & 7;
    const int rB = rA + 32;

    const int bh = blockIdx.x;
    const int r0 = blockIdx.y << 6;

    const unsigned short* __restrict__ Bq = wsu + 4 * (size_t)SEG + (size_t)bh * NDn;
    const unsigned short* __restrict__ qh   = Bq;                    // t2=0
    const unsigned short* __restrict__ kh   = Bq + 2 * (size_t)SEG;  // t2=1
    const unsigned short* __restrict__ vth  = Bq + 4 * (size_t)SEG;  // t2=2 [d][n]
    const unsigned short* __restrict__ qjh  = Bq + 6 * (size_t)SEG;  // t2=3
    const unsigned short* __restrict__ kjh  = Bq + 8 * (size_t)SEG;  // t2=4
    const unsigned short* __restrict__ vjth = Bq + 10 * (size_t)SEG; // t2=5 [d][n]

    // ---- Prologue: Q/QJ fragments
    bf16x8 qhi[2], qlo[2], qjhi[2], qjlo[2];
    {
        const int qrow = r0 + w * 16 + l15;
#pragma unroll
        for (int c = 0; c < 2; ++c) {
            const size_t o = (size_t)qrow * 64 + c * 32 + h4 * 8;
            qhi[c] = *(const bf16x8*)(qh + o);
            qlo[c] = *(const bf16x8*)(qh + SEG + o);
            qjhi[c] = *(const bf16x8*)(qjh + o);
            qjlo[c] = *(const bf16x8*)(qjh + SEG + o);
        }
    }

    f32x4 mold = {-3.0e38f, -3.0e38f, -3.0e38f, -3.0e38f};
    f32x4 l_run = {0.f, 0.f, 0.f, 0.f};
    f32x4 ar_run = {0.f, 0.f, 0.f, 0.f};
    f32x4 ax[4], ac[4], ad[4];
#pragma unroll
    for (int ds = 0; ds < 4; ++ds) {
        ax[ds] = (f32x4){0.f, 0.f, 0.f, 0.f};
        ac[ds] = (f32x4){0.f, 0.f, 0.f, 0.f};
        ad[ds] = (f32x4){0.f, 0.f, 0.f, 0.f};
    }

    bf16x8 kr0[4], kr1[4], vr0[4], vr1[4];
    const int ba = rA * 128 + ((ss ^ (rA & 7)) << 4);
    const int bb = rB * 128 + ((ss ^ (rA & 7)) << 4);   // rB&7 == rA&7

#define A_LOADK(JT_) {                                                         \
    const size_t ga = (size_t)((JT_) + rA) * 64 + 8 * ss;                      \
    const size_t gb = (size_t)((JT_) + rB) * 64 + 8 * ss;                      \
    kr0[0] = *(const bf16x8*)(kh + ga);        kr1[0] = *(const bf16x8*)(kh + gb); \
    kr0[1] = *(const bf16x8*)(kh + SEG + ga);  kr1[1] = *(const bf16x8*)(kh + SEG + gb); \
    kr0[2] = *(const bf16x8*)(kjh + ga);       kr1[2] = *(const bf16x8*)(kjh + gb); \
    kr0[3] = *(const bf16x8*)(kjh + SEG + ga); kr1[3] = *(const bf16x8*)(kjh + SEG + gb); }

#define A_LOADV(JT_) {                                                         \
    const size_t ga = (size_t)rA * Nn + (JT_) + 8 * ss;                        \
    const size_t gb = (size_t)rB * Nn + (JT_) + 8 * ss;                        \
    vr0[0] = *(const bf16x8*)(vth + ga);        vr1[0] = *(const bf16x8*)(vth + gb); \
    vr0[1] = *(const bf16x8*)(vth + SEG + ga);  vr1[1] = *(const bf16x8*)(vth + SEG + gb); \
    vr0[2] = *(const bf16x8*)(vjth + ga);       vr1[2] = *(const bf16x8*)(vjth + gb); \
    vr0[3] = *(const bf16x8*)(vjth + SEG + ga); vr1[3] = *(const bf16x8*)(vjth + SEG + gb); }

#define A_WRITE(R0_, R1_) {                                                    \
    *(bf16x8*)((char*)sKV[0] + ba) = R0_[0]; *(bf16x8*)((char*)sKV[0] + bb) = R1_[0]; \
    *(bf16x8*)((char*)sKV[1] + ba) = R0_[1]; *(bf16x8*)((char*)sKV[1] + bb) = R1_[1]; \
    *(bf16x8*)((char*)sKV[2] + ba) = R0_[2]; *(bf16x8*)((char*)sKV[2] + bb) = R1_[2]; \
    *(bf16x8*)((char*)sKV[3] + ba) = R0_[3]; *(bf16x8*)((char*)sKV[3] + bb) = R1_[3]; }

    A_LOADK(0);

    for (int jt = 0; jt < Nn; jt += 64) {
        __syncthreads();                       // (a) sKV free (prev PV done)
        A_WRITE(kr0, kr1);
        __syncthreads();                       // (b)

        // ---- S, DM via split-bf16 MFMA
        f32x4 S[4], DM[4];
        __builtin_amdgcn_s_setprio(1);
#pragma unroll
        for (int kt = 0; kt < 4; ++kt) {
            f32x4 s = {0.f, 0.f, 0.f, 0.f};
            f32x4 dm = {0.f, 0.f, 0.f, 0.f};
#pragma unroll
            for (int c = 0; c < 2; ++c) {
                const int boff = (l15 + (kt << 4)) * 128 + (((h4 << 4) | (c << 6)) ^ sw);
                const bf16x8 khi = ldfrag(sKV[0], boff);
                const bf16x8 klo = ldfrag(sKV[1], boff);
                const bf16x8 jhi = ldfrag(sKV[2], boff);
                const bf16x8 jlo = ldfrag(sKV[3], boff);
                s = MFMA(qhi[c], khi, s);
                s = MFMA(qhi[c], klo, s);
                s = MFMA(qlo[c], khi, s);
                dm = MFMA(qjhi[c], khi, dm);
                dm = MFMA(qjhi[c], klo, dm);
                dm = MFMA(qjlo[c], khi, dm);
                dm = MFMA(qhi[c], jhi, dm);
                dm = MFMA(qhi[c], jlo, dm);
                dm = MFMA(qlo[c], jhi, dm);
            }
            S[kt] = s; DM[kt] = dm;
        }
        __builtin_amdgcn_s_setprio(0);

        // T14: issue V(jt) + next K loads; latency hides under softmax
        A_LOADV(jt);
        A_LOADK((jt + 64) & (Nn - 1));

        // ---- online softmax update
        f32x4 tmax, mnew, alpha;
#pragma unroll
        for (int r = 0; r < 4; ++r)
            tmax[r] = fmaxf(fmaxf(S[0][r], S[1][r]), fmaxf(S[2][r], S[3][r]));
#pragma unroll
        for (int m = 1; m < 16; m <<= 1)
#pragma unroll
            for (int r = 0; r < 4; ++r)
                tmax[r] = fmaxf(tmax[r], __shfl_xor(tmax[r], m));
#pragma unroll
        for (int r = 0; r < 4; ++r) {
            mnew[r] = fmaxf(mold[r], tmax[r]);
            alpha[r] = __expf(mold[r] - mnew[r]);
            mold[r] = mnew[r];
        }
        f32x4 lsum = {0.f, 0.f, 0.f, 0.f};
        f32x4 arsum = {0.f, 0.f, 0.f, 0.f};
#pragma unroll
        for (int kt = 0; kt < 4; ++kt) {
            const int key = (kt << 4) + l15;
#pragma unroll
            for (int r = 0; r < 4; ++r) {
                const float p = __expf(S[kt][r] - mnew[r]);
                const float pd = p * DM[kt][r];
                lsum[r] += p;
                arsum[r] += pd;
                const int qq = (h4 << 2) + r;
                const int boff = qq * 128 +
                    (((key & 7) << 1) | ((((key >> 3) ^ (qq & 7)) << 4)));
                const unsigned short ph = f2bf(p);
                const unsigned short pdh = f2bf(pd);
                *(unsigned short*)((char*)sP[w][0] + boff) = ph;
                *(unsigned short*)((char*)sP[w][1] + boff) = f2bf(p - bf2f(ph));
                *(unsigned short*)((char*)sP[w][2] + boff) = pdh;
                *(unsigned short*)((char*)sP[w][3] + boff) = f2bf(pd - bf2f(pdh));
            }
        }
#pragma unroll
        for (int r = 0; r < 4; ++r) {
            l_run[r] = l_run[r] * alpha[r] + lsum[r];
            ar_run[r] = ar_run[r] * alpha[r] + arsum[r];
        }
#pragma unroll
        for (int ds = 0; ds < 4; ++ds) {
            ax[ds] *= alpha; ac[ds] *= alpha; ad[ds] *= alpha;
        }

        __syncthreads();                       // (c) all waves done K reads
        A_WRITE(vr0, vr1);                     // V^T tile, pure b128 copies
        __syncthreads();                       // (d)

        // ---- PV: x += P.V ; xc += P.VJ ; xd += (P*dm).V
        __builtin_amdgcn_s_setprio(1);
#pragma unroll
        for (int kc = 0; kc < 2; ++kc) {
            const int pxo = ((h4 << 4) | (kc << 6)) ^ sw;
            const bf16x8 phi = ldfrag(sP[w][0], l15 * 128 + pxo);
            const bf16x8 plo = ldfrag(sP[w][1], l15 * 128 + pxo);
            const bf16x8 dhi = ldfrag(sP[w][2], l15 * 128 + pxo);
            const bf16x8 dlo = ldfrag(sP[w][3], l15 * 128 + pxo);
#pragma unroll
            for (int ds = 0; ds < 4; ++ds) {
                const int boff = (l15 + (ds << 4)) * 128 + pxo;
                const bf16x8 vhi = ldfrag(sKV[0], boff);
                const bf16x8 vlo = ldfrag(sKV[1], boff);
                const bf16x8 wjh = ldfrag(sKV[2], boff);
                const bf16x8 wjl = ldfrag(sKV[3], boff);
                ax[ds] = MFMA(phi, vhi, ax[ds]);
                ax[ds] = MFMA(phi, vlo, ax[ds]);
                ax[ds] = MFMA(plo, vhi, ax[ds]);
                ac[ds] = MFMA(phi, wjh, ac[ds]);
                ac[ds] = MFMA(phi, wjl, ac[ds]);
                ac[ds] = MFMA(plo, wjh, ac[ds]);
                ad[ds] = MFMA(dhi, vhi, ad[ds]);
                ad[ds] = MFMA(dhi, vlo, ad[ds]);
                ad[ds] = MFMA(dlo, vhi, ad[ds]);
            }
        }
        __builtin_amdgcn_s_setprio(0);
    }

    // ---- Epilogue: normalize, JVP correction, store x/xj as hi/lo bf16
#pragma unroll
    for (int m = 1; m < 16; m <<= 1)
#pragma unroll
        for (int r = 0; r < 4; ++r) {
            l_run[r] += __shfl_xor(l_run[r], m);
            ar_run[r] += __shfl_xor(ar_run[r], m);
        }
    const int b = bh / Hn;
    const int hh = bh - b * Hn;
    unsigned short* __restrict__ xh = wsu;
    unsigned short* __restrict__ xl = wsu + (size_t)SEG;
    unsigned short* __restrict__ xjh = wsu + 2 * (size_t)SEG;
    unsigned short* __restrict__ xjl = wsu + 3 * (size_t)SEG;
#pragma unroll
    for (int r = 0; r < 4; ++r) {
        const int qg = r0 + w * 16 + (h4 << 2) + r;
        const float invl = 1.0f / l_run[r];
        const float rowv = ar_run[r] * invl;
        const size_t base = ((size_t)(b * Nn + qg)) * Cn + hh * Dn + l15;
#pragma unroll
        for (int ds = 0; ds < 4; ++ds) {
            const float x = ax[ds][r] * invl;
            const float xjv = fmaf(-rowv, x, (ad[ds][r] + ac[ds][r]) * invl);
            const size_t ad2 = base + ds * 16;
            const unsigned short h0 = f2bf(x);
            xh[ad2] = h0;
            xl[ad2] = f2bf(x - bf2f(h0));
            const unsigned short h1 = f2bf(xjv);
            xjh[ad2] = h1;
            xjl[ad2] = f2bf(xjv - bf2f(h1));
        }
    }
}

extern "C" void kernel_launch(void* const* d_in, const int* in_sizes, int n_in,
                              void* d_out, int out_size, void* d_ws, size_t ws_size,
                              hipStream_t stream)
{
    const float* input  = (const float*)d_in[0];
    const float* inputj = (const float*)d_in[1];
    const float* W_qkv  = (const float*)d_in[2];
    const float* W_proj = (const float*)d_in[3];
    const float* b_proj = (const float*)d_in[4];
    float* out = (float*)d_out;
    unsigned short* wsu = (unsigned short*)d_ws;
    unsigned short* regA = wsu;                      // IN splits -> x splits
    unsigned short* regB = wsu + 4 * (size_t)SEG;    // qkv splits (12 segs)
    unsigned short* wqh = (unsigned short*)d_out;    // W_qkv split scratch in d_out
    unsigned short* wql = wqh + (size_t)WQ_ELE;      // (overwritten by final GEMM)
    unsigned short* wph = regB;                      // W_proj split (after attn)
    unsigned short* wpl = wph + (size_t)WP_ELE;

    // 1) split inputs and W_qkv into hi/lo bf16
    conv_k<<<2 * (SEG / 4) / 256, 256, 0, stream>>>(input, inputj, regA);
    conv_w<<<(WQ_ELE / 4) / 256, 256, 0, stream>>>(W_qkv, wqh, wql);
    // 2) qkv = IN @ W_qkv^T  (MFMA; scatter hi/lo, scale q, transpose v)
    gemm_mfma<0><<<dim3(18, 32, 2), 256, 0, stream>>>(regA, wqh, wql, nullptr,
                                                      regB, nullptr);
    // 3) fused attention + softmax JVP (writes x/xj hi/lo into region A)
    attn_mfma<<<dim3(48, 16), 256, 0, stream>>>(wsu);
    // 4) split W_proj (region B now free), then out = x @ W_proj^T (+bias)
    conv_w<<<(WP_ELE / 4) / 256, 256, 0, stream>>>(W_proj, wph, wpl);
    gemm_mfma<1><<<dim3(6, 32, 2), 256, 0, stream>>>(regA, wph, wpl, b_proj,
                                                     nullptr, out);
}